// Round 1
// baseline (103.610 us; speedup 1.0000x reference)
//
#include <hip/hip_runtime.h>
#include <math.h>

// ConditionalInstanceNorm1D: x[B,C,L] fp32, weight[S,C], bias[S,C], style_ids[B] int
// out = (x - mean_row) * rsqrt(var_row + eps) * w[sid,c] + b[sid,c]
// One block per (b,c) row. L=8192, 256 threads, 32 floats/thread in registers.

constexpr int L_LEN  = 8192;
constexpr int NTHR   = 256;
constexpr int VPT    = L_LEN / (NTHR * 4);   // float4 loads per thread = 8
constexpr float EPS_ = 1e-5f;

__global__ __launch_bounds__(NTHR) void cin1d_kernel(
    const float* __restrict__ x,
    const float* __restrict__ weight,
    const float* __restrict__ bias,
    const int*   __restrict__ style_ids,
    float* __restrict__ out,
    int C)
{
    const int row = blockIdx.x;          // row = b*C + c
    const int b   = row / C;
    const int c   = row - b * C;
    const float4* __restrict__ xr  = reinterpret_cast<const float4*>(x + (size_t)row * L_LEN);
    float4* __restrict__       outr = reinterpret_cast<float4*>(out + (size_t)row * L_LEN);
    const int t = threadIdx.x;

    // Load row into registers (coalesced float4), accumulate sum & sumsq.
    float4 v[VPT];
    float sum = 0.f, sq = 0.f;
#pragma unroll
    for (int i = 0; i < VPT; ++i) {
        v[i] = xr[t + i * NTHR];
        sum += v[i].x + v[i].y + v[i].z + v[i].w;
        sq  += v[i].x * v[i].x + v[i].y * v[i].y + v[i].z * v[i].z + v[i].w * v[i].w;
    }

    // Wave(64)-level butterfly reduce.
#pragma unroll
    for (int off = 32; off > 0; off >>= 1) {
        sum += __shfl_down(sum, off, 64);
        sq  += __shfl_down(sq,  off, 64);
    }

    __shared__ float s_sum[NTHR / 64];
    __shared__ float s_sq[NTHR / 64];
    __shared__ float s_scale, s_shift;
    const int wave = t >> 6;
    const int lane = t & 63;
    if (lane == 0) { s_sum[wave] = sum; s_sq[wave] = sq; }
    __syncthreads();

    if (t == 0) {
        float ts = 0.f, tq = 0.f;
#pragma unroll
        for (int wv = 0; wv < NTHR / 64; ++wv) { ts += s_sum[wv]; tq += s_sq[wv]; }
        const float inv_n = 1.0f / (float)L_LEN;
        const float mean  = ts * inv_n;
        const float var   = tq * inv_n - mean * mean;
        const float rstd  = rsqrtf(var + EPS_);
        const int   sid   = style_ids[b];
        const float w     = weight[sid * C + c];
        const float bb    = bias[sid * C + c];
        s_scale = w * rstd;
        s_shift = bb - mean * w * rstd;
    }
    __syncthreads();

    const float scale = s_scale;
    const float shift = s_shift;
#pragma unroll
    for (int i = 0; i < VPT; ++i) {
        float4 o;
        o.x = v[i].x * scale + shift;
        o.y = v[i].y * scale + shift;
        o.z = v[i].z * scale + shift;
        o.w = v[i].w * scale + shift;
        outr[t + i * NTHR] = o;
    }
}

extern "C" void kernel_launch(void* const* d_in, const int* in_sizes, int n_in,
                              void* d_out, int out_size, void* d_ws, size_t ws_size,
                              hipStream_t stream) {
    const float* x      = (const float*)d_in[0];
    const float* weight = (const float*)d_in[1];
    const float* bias   = (const float*)d_in[2];
    const int*   sids   = (const int*)d_in[3];
    float*       out    = (float*)d_out;

    const int B = in_sizes[3];                 // style_ids has B elements
    const int C = in_sizes[0] / (B * L_LEN);   // x = B*C*L
    const int rows = B * C;                    // 8192 blocks

    cin1d_kernel<<<rows, NTHR, 0, stream>>>(x, weight, bias, sids, out, C);
}

// Round 2
// 96.354 us; speedup vs baseline: 1.0753x; 1.0753x over previous
//
#include <hip/hip_runtime.h>
#include <math.h>

// ConditionalInstanceNorm1D: x[B,C,L] fp32, weight[S,C], bias[S,C], style_ids[B] int
// out = (x - mean_row) * rsqrt(var_row + eps) * w[sid,c] + b[sid,c]
// One block per (b,c) row. L=8192. 512 threads, 16 floats/thread in registers.
// Single HBM read + single HBM write (register-resident row), non-temporal hints.

constexpr int L_LEN  = 8192;
constexpr int NTHR   = 512;
constexpr int VPT    = L_LEN / (NTHR * 4);   // float4 loads per thread = 4
constexpr int NWAVE  = NTHR / 64;            // 8 waves
constexpr float EPS_ = 1e-5f;

typedef float f32x4 __attribute__((ext_vector_type(4)));

__global__ __launch_bounds__(NTHR) void cin1d_kernel(
    const float* __restrict__ x,
    const float* __restrict__ weight,
    const float* __restrict__ bias,
    const int*   __restrict__ style_ids,
    float* __restrict__ out,
    int C)
{
    const int row = blockIdx.x;          // row = b*C + c
    const int b   = row / C;
    const int c   = row - b * C;
    const f32x4* __restrict__ xr   = reinterpret_cast<const f32x4*>(x + (size_t)row * L_LEN);
    f32x4* __restrict__       outr = reinterpret_cast<f32x4*>(out + (size_t)row * L_LEN);
    const int t = threadIdx.x;

    // Load row into registers (coalesced 16B, non-temporal), accumulate sum & sumsq.
    f32x4 v[VPT];
    float sum = 0.f, sq = 0.f;
#pragma unroll
    for (int i = 0; i < VPT; ++i) {
        v[i] = __builtin_nontemporal_load(&xr[t + i * NTHR]);
        sum += v[i].x + v[i].y + v[i].z + v[i].w;
        sq  += v[i].x * v[i].x + v[i].y * v[i].y + v[i].z * v[i].z + v[i].w * v[i].w;
    }

    // Wave(64)-level butterfly reduce.
#pragma unroll
    for (int off = 32; off > 0; off >>= 1) {
        sum += __shfl_down(sum, off, 64);
        sq  += __shfl_down(sq,  off, 64);
    }

    __shared__ float s_sum[NWAVE];
    __shared__ float s_sq[NWAVE];
    __shared__ float s_scale, s_shift;
    const int wave = t >> 6;
    const int lane = t & 63;
    if (lane == 0) { s_sum[wave] = sum; s_sq[wave] = sq; }
    __syncthreads();

    if (t == 0) {
        float ts = 0.f, tq = 0.f;
#pragma unroll
        for (int wv = 0; wv < NWAVE; ++wv) { ts += s_sum[wv]; tq += s_sq[wv]; }
        const float inv_n = 1.0f / (float)L_LEN;
        const float mean  = ts * inv_n;
        const float var   = tq * inv_n - mean * mean;
        const float rstd  = rsqrtf(var + EPS_);
        const int   sid   = style_ids[b];
        const float w     = weight[sid * C + c];
        const float bb    = bias[sid * C + c];
        s_scale = w * rstd;
        s_shift = bb - mean * w * rstd;
    }
    __syncthreads();

    const float scale = s_scale;
    const float shift = s_shift;
#pragma unroll
    for (int i = 0; i < VPT; ++i) {
        f32x4 o;
        o.x = v[i].x * scale + shift;
        o.y = v[i].y * scale + shift;
        o.z = v[i].z * scale + shift;
        o.w = v[i].w * scale + shift;
        __builtin_nontemporal_store(o, &outr[t + i * NTHR]);
    }
}

extern "C" void kernel_launch(void* const* d_in, const int* in_sizes, int n_in,
                              void* d_out, int out_size, void* d_ws, size_t ws_size,
                              hipStream_t stream) {
    const float* x      = (const float*)d_in[0];
    const float* weight = (const float*)d_in[1];
    const float* bias   = (const float*)d_in[2];
    const int*   sids   = (const int*)d_in[3];
    float*       out    = (float*)d_out;

    const int B = in_sizes[3];                 // style_ids has B elements
    const int C = in_sizes[0] / (B * L_LEN);   // x = B*C*L
    const int rows = B * C;                    // 8192 blocks

    cin1d_kernel<<<rows, NTHR, 0, stream>>>(x, weight, bias, sids, out, C);
}